// Round 6
// baseline (181.901 us; speedup 1.0000x reference)
//
#include <hip/hip_runtime.h>
#include <hip/hip_bf16.h>

typedef __bf16 bf16;
typedef __attribute__((ext_vector_type(4)))  __bf16 bf16x4;
typedef __attribute__((ext_vector_type(8)))  __bf16 bf16x8;
typedef __attribute__((ext_vector_type(16))) float  f32x16;

#define B_   512
#define NC_  512
#define K_   4
#define S_   8
#define H_   128
#define D_   64
#define XROW (NC_ * K_)
#define NITER 32        // 512 items / (2 groups * 8 items/iter)

// pi: swap bits 2,3 of within-32 index (involution). Hidden dims stored
// physically permuted so the 32x32 MFMA C/D register layout of layer k IS
// the B-fragment layout of layer k+1 (r3/r5/r8-verified algebra).
static __device__ __forceinline__ int swap23(int v) {
    return (v & ~12) | ((v & 4) << 1) | ((v & 8) >> 1);
}

// Round-6: H-QUARTER split, 512-thread blocks. Round-5 lesson: occupancy is
// register-quantized -- the pair-split wave's 76 arch + ~80 acc = 156 total
// rounds to 192 -> 2 waves/SIMD (25% occ) regardless of LDS. Fix: 8 waves =
// 2 item-groups x 4 H-quarter waves; per wave ONE A (16 acc), ONE C (16),
// L (16) -> acc peak 32, arch ~85, total ~116 -> quantizes to 128 ->
// 4 waves/SIMD. 2 blocks/CU (LDS 56 KB) -> 16 waves/CU = 50% occupancy.
// Same verified algebra: row-group 2h+aa -> q, chunk 4h+tt -> 2q+e.
__global__ __launch_bounds__(512, 4)
void jt_mlp_kernel(const int*   __restrict__ x,
                   const float* __restrict__ W1g, const float* __restrict__ b1g,
                   const float* __restrict__ W2g, const float* __restrict__ b2g,
                   const float* __restrict__ W3g, const float* __restrict__ b3g,
                   float* __restrict__ out)
{
    // Swizzled weights: element (row p, k) at p*rowlen + ch*8 + (k&7),
    //   W1: ch = (k>>3) ^ (p&7)
    //   W2: ch = (k>>3) ^ (p&15) ^ ((p&16)>>2)   (5th bit: kills the
    //       l31 vs l31+16 same-bank alias -> 8-access/bank minimum)
    __shared__ __align__(16) bf16 SW2[128 * 128];   // 32 KB
    __shared__ __align__(16) bf16 SWX[128 * 64];    // 16 KB: W1 staging, then HX
    __shared__ __align__(16) bf16 SW3[8 * 128];     // 2 KB
    __shared__ __align__(16) float LX[2][3][64][4]; // 6 KB (q>0 write, q==0 read)

    const int tid  = threadIdx.x;
    const int lane = tid & 63;
    const int ws   = __builtin_amdgcn_readfirstlane(tid >> 6);  // 0..7 scalar
    const int g    = ws >> 2;       // item group 0,1
    const int qs   = ws & 3;        // H quarter 0..3 (rows 32qs..32qs+31)
    const int l31  = lane & 31;
    const int lhi  = lane >> 5;
    const int kk   = l31 & 3;
    const int n    = blockIdx.x;    // clique (512 blocks, 2 resident/CU)

    const float* W1p = W1g + (size_t)n * (D_ * H_);
    const float* W2p = W2g + (size_t)n * (H_ * H_);
    const float* W3p = W3g + (size_t)n * (H_ * S_);
    const float* b1p = b1g + n * H_;
    const float* b2p = b2g + n * H_;
    const float* b3p = b3g + n * S_;

    const int p31 = swap23(l31);
    const bf16 one = (bf16)1.0f, zero = (bf16)0.0f;

    // ============ stage weights into LDS (coalesced float4; r8-proven) ============
    // W1 -> SWX (temporarily), staged by tid<256. k<8 rows carry +b1;
    // root n==0 zeroes k<32 first.
    if (tid < 256) {
        const int c0 = (tid & 31) * 4;
        const int k0 = (tid >> 5) * 8;          // 0..56
        float rows[8][4];
#pragma unroll
        for (int i = 0; i < 8; ++i) {
            float4 t4 = *(const float4*)(W1p + (k0 + i) * H_ + c0);
            if (n == 0 && k0 < 32) t4 = make_float4(0.f, 0.f, 0.f, 0.f);
            rows[i][0] = t4.x; rows[i][1] = t4.y; rows[i][2] = t4.z; rows[i][3] = t4.w;
        }
        if (k0 == 0) {
            const float4 bb = *(const float4*)(b1p + c0);
#pragma unroll
            for (int i = 0; i < 8; ++i) {
                rows[i][0] += bb.x; rows[i][1] += bb.y;
                rows[i][2] += bb.z; rows[i][3] += bb.w;
            }
        }
#pragma unroll
        for (int j2 = 0; j2 < 4; ++j2) {
            const int c = c0 + j2;
            const int p = (c & ~31) | swap23(c & 31);
            const int ch = (k0 >> 3) ^ (p & 7);
            bf16x4 lo, hi;
#pragma unroll
            for (int i = 0; i < 4; ++i) {
                lo[i] = (bf16)rows[i][j2];
                hi[i] = (bf16)rows[4 + i][j2];
            }
            *(bf16x4*)&SWX[p * 64 + ch * 8 + 0] = lo;
            *(bf16x4*)&SWX[p * 64 + ch * 8 + 4] = hi;
        }
    }
    // W2 -> SW2 (5-bit swizzle): all 512 threads, one 8-row block each
    {
        const int c0 = (tid & 31) * 4;
        const int k0 = (tid >> 5) * 8;          // 0..120
        float rows[8][4];
#pragma unroll
        for (int i = 0; i < 8; ++i) {
            const float4 t4 = *(const float4*)(W2p + (k0 + i) * H_ + c0);
            rows[i][0] = t4.x; rows[i][1] = t4.y; rows[i][2] = t4.z; rows[i][3] = t4.w;
        }
#pragma unroll
        for (int j2 = 0; j2 < 4; ++j2) {
            const int c = c0 + j2;
            const int p = (c & ~31) | swap23(c & 31);
            const int ch = (k0 >> 3) ^ (p & 15) ^ ((p & 16) >> 2);
            bf16x4 lo, hi;
#pragma unroll
            for (int i = 0; i < 4; ++i) {
                lo[i] = (bf16)rows[i][j2];
                hi[i] = (bf16)rows[4 + i][j2];
            }
            *(bf16x4*)&SW2[p * 128 + ch * 8 + 0] = lo;
            *(bf16x4*)&SW2[p * 128 + ch * 8 + 4] = hi;
        }
    }
    // W3^T[s][k] -> SW3
    if (tid < 128) {
        const int s = tid >> 4, kc = tid & 15, k0 = kc * 8;
        float vv[8];
#pragma unroll
        for (int i = 0; i < 8; ++i) vv[i] = W3p[(k0 + i) * S_ + s];
        const int ch = kc ^ s;
        bf16x4 lo, hi;
#pragma unroll
        for (int i = 0; i < 4; ++i) { lo[i] = (bf16)vv[i]; hi[i] = (bf16)vv[4 + i]; }
        *(bf16x4*)&SW3[s * 128 + ch * 8 + 0] = lo;
        *(bf16x4*)&SW3[s * 128 + ch * 8 + 4] = hi;
    }
    __syncthreads();

    // ---- W1 fragments for this wave's H-quarter (rows 32qs..32qs+31) ----
    bf16x8 w1f[4];
#pragma unroll
    for (int kt = 0; kt < 4; ++kt)
        w1f[kt] = *(const bf16x8*)
            &SWX[(32 * qs + l31) * 64 + (((kt << 1) + lhi) ^ (l31 & 7)) * 8];
    // ---- W3 fragments (this wave's chunks 2qs, 2qs+1) ----
    const int s2 = l31 & 7;   // lanes 8..31 duplicate state rows (outputs unused)
    bf16x8 w3f[2];
#pragma unroll
    for (int e = 0; e < 2; ++e)
        w3f[e] = *(const bf16x8*)
            &SW3[s2 * 128 + ((((2 * qs + e) << 1) + lhi) ^ s2) * 8];
    // ---- bias frags ----
    bf16x8 w2b, onef;
#pragma unroll
    for (int j = 0; j < 8; ++j) { w2b[j] = zero; onef[j] = zero; }
    w2b[0] = lhi ? zero : (bf16)b2p[32 * qs + p31];
    onef[0] = lhi ? zero : one;
    const float4 b3q = *(const float4*)(b3p + 4 * lhi);

    f32x16 zf;
#pragma unroll
    for (int i = 0; i < 16; ++i) zf[i] = 0.f;

    __syncthreads();   // w1f/w3f reads done -> SWX becomes the HX buffer
    bf16* HX = SWX;    // HX[g][gc][lane][8] = (g*8+gc)*512 + lane*8  (16 slots)

    // -------- x prefetch --------
    const int itbase = g * 8 + (l31 >> 2);
    int4 xo_c, xp_c;
    {
        const int* xb = x + (size_t)itbase * XROW + n * K_;
        xo_c = *(const int4*)xb;
        xp_c = (n > 0) ? *(const int4*)(xb - K_) : make_int4(0, 0, 0, 0);
    }

    const int swz = (l31 & 15) ^ ((l31 & 16) >> 2);
    const int pq  = (32 * qs + l31) * 128;    // W2 row base (C rows 32qs..+31)
    const int g8  = g * 8;

#pragma unroll 1
    for (int c = 0; c < NITER; ++c) {
        const int item = itbase + c * 16;
        const int4 xo = xo_c, xp = xp_c;
        if (c < NITER - 1) {
            const int* xb = x + (size_t)(item + 16) * XROW + n * K_;
            xo_c = *(const int4*)xb;
            xp_c = (n > 0) ? *(const int4*)(xb - K_) : make_int4(0, 0, 0, 0);
        }

        // ---- one-hot selectors (r3/r5-proven) ----
        int sel[4];
        sel[0] = (n > 0) ? (lhi ? xp.y : xp.x) : (lhi ? -1 : 0);
        sel[1] = (n > 0) ? (lhi ? xp.w : xp.z) : -1;
        sel[2] = (kk > (lhi ? 1 : 0)) ? (lhi ? xo.y : xo.x) : -1;
        sel[3] = (kk > (lhi ? 3 : 2)) ? (lhi ? xo.w : xo.z) : -1;

        // ---- layer 1: own H-quarter (single acc chain) ----
        f32x16 A = zf;
#pragma unroll
        for (int kt = 0; kt < 4; ++kt) {
            bf16x8 bf1;
#pragma unroll
            for (int j = 0; j < 8; ++j) bf1[j] = (sel[kt] == j) ? one : zero;
            A = __builtin_amdgcn_mfma_f32_32x32x16_bf16(w1f[kt], bf1, A, 0, 0, 0);
        }

        // ---- extract own 2 chunks (2qs, 2qs+1), publish to group ----
        bf16x8 hfo[2];
#pragma unroll
        for (int e = 0; e < 2; ++e) {
#pragma unroll
            for (int j = 0; j < 8; ++j)
                hfo[e][j] = (bf16)fmaxf(A[8 * e + j], 0.f);
            *(bf16x8*)&HX[(g8 + 2 * qs + e) * 512 + lane * 8] = hfo[e];
        }
        __syncthreads();

        // ---- layer 2: own C rows 32qs..+31; full K via group chunks ----
        f32x16 C = __builtin_amdgcn_mfma_f32_32x32x16_bf16(w2b, onef, zf, 0, 0, 0);
#pragma unroll
        for (int gc = 0; gc < 8; ++gc) {
            bf16x8 hf;
            if (qs == (gc >> 1)) {
                hf = hfo[gc & 1];
            } else {
                hf = *(const bf16x8*)&HX[(g8 + gc) * 512 + lane * 8];
            }
            const int chunk = ((gc << 1) + lhi) ^ swz;
            const bf16x8 f = *(const bf16x8*)&SW2[pq + chunk * 8];
            C = __builtin_amdgcn_mfma_f32_32x32x16_bf16(f, hf, C, 0, 0, 0);
        }

        // ---- layer 3 partial over own 2 chunks ----
        f32x16 L = zf;
#pragma unroll
        for (int e = 0; e < 2; ++e) {
            bf16x8 hg;
#pragma unroll
            for (int j = 0; j < 8; ++j)
                hg[j] = (bf16)fmaxf(C[8 * e + j], 0.f);
            L = __builtin_amdgcn_mfma_f32_32x32x16_bf16(w3f[e], hg, L, 0, 0, 0);
        }

        // ---- 4-way partial sum; epilogue on qs==0 ----
        if (qs != 0)
            *(float4*)&LX[g][qs - 1][lane][0] = make_float4(L[0], L[1], L[2], L[3]);
        __syncthreads();
        if (qs == 0) {
            const float4 P0 = *(const float4*)&LX[g][0][lane][0];
            const float4 P1 = *(const float4*)&LX[g][1][lane][0];
            const float4 P2 = *(const float4*)&LX[g][2][lane][0];
            float Ls0 = L[0] + P0.x + P1.x + P2.x + b3q.x;
            float Ls1 = L[1] + P0.y + P1.y + P2.y + b3q.y;
            float Ls2 = L[2] + P0.z + P1.z + P2.z + b3q.z;
            float Ls3 = L[3] + P0.w + P1.w + P2.w + b3q.w;

            float m4 = fmaxf(fmaxf(Ls0, Ls1), fmaxf(Ls2, Ls3));
            const float mm = fmaxf(m4, __shfl_xor(m4, 32));
            float e = __expf(Ls0 - mm) + __expf(Ls1 - mm) +
                      __expf(Ls2 - mm) + __expf(Ls3 - mm);
            const float ssum = e + __shfl_xor(e, 32);

            const int xs = (kk & 2) ? ((kk & 1) ? xo.w : xo.z)
                                    : ((kk & 1) ? xo.y : xo.x);
            const float own = (xs & 2) ? ((xs & 1) ? Ls3 : Ls2)
                                       : ((xs & 1) ? Ls1 : Ls0);
            const float oth = __shfl_xor(own, 32);
            const float obs = ((xs >> 2) == lhi) ? own : oth;
            float lp = obs - mm - __logf(ssum);
            lp += __shfl_xor(lp, 1);
            lp += __shfl_xor(lp, 2);
            if (lhi == 0 && kk == 0)
                out[(size_t)item * NC_ + n] = lp;
        }
        // HX overwrite next iter is safe: all HX reads complete before the
        // second barrier; LX reads (qs==0) complete before the next first
        // barrier (writers can't pass it until qs==0 arrives too).
    }
}

extern "C" void kernel_launch(void* const* d_in, const int* in_sizes, int n_in,
                              void* d_out, int out_size, void* d_ws, size_t ws_size,
                              hipStream_t stream) {
    const int*   x  = (const int*)d_in[0];
    const float* W1 = (const float*)d_in[1];
    const float* b1 = (const float*)d_in[2];
    const float* W2 = (const float*)d_in[3];
    const float* b2 = (const float*)d_in[4];
    const float* W3 = (const float*)d_in[5];
    const float* b3 = (const float*)d_in[6];
    float* out = (float*)d_out;
    jt_mlp_kernel<<<dim3(NC_), 512, 0, stream>>>(x, W1, b1, W2, b2, W3, b3, out);
}

// Round 7
// 165.140 us; speedup vs baseline: 1.1015x; 1.1015x over previous
//
#include <hip/hip_runtime.h>
#include <hip/hip_bf16.h>

typedef __bf16 bf16;
typedef __attribute__((ext_vector_type(4)))  __bf16 bf16x4;
typedef __attribute__((ext_vector_type(8)))  __bf16 bf16x8;
typedef __attribute__((ext_vector_type(16))) float  f32x16;

#define B_   512
#define NC_  512
#define K_   4
#define S_   8
#define H_   128
#define D_   64
#define XROW (NC_ * K_)
#define NITER 32        // 512 items / (2 groups * 8 items/iter)

// pi: swap bits 2,3 of within-32 index (involution). Hidden dims stored
// physically permuted so the 32x32 MFMA C/D register layout of layer k IS
// the B-fragment layout of layer k+1 (r3/r5/r8-verified algebra).
static __device__ __forceinline__ int swap23(int v) {
    return (v & ~12) | ((v & 4) << 1) | ((v & 8) >> 1);
}

// Round-7: VALU diet on the round-6 H-quarter structure. Round-6 counters
// (VALU 50%, Mfma 24%) showed the kernel is VALU-bound on the one-hot
// fragment build, which the 4-way H-split duplicates in every wave.
// Fix 1: ONE-HOT LUT -- only 9 possible B-fragments exist (sel=-1,0..7);
// stage them once in LDS (144 B) and fetch with one ds_read_b128 per kt
// (broadcast for equal sel) instead of ~25 cmp/cndmask VALU ops.
// Fix 2: layer-2 reads all 8 h1 chunks uniformly from HX (no if-converted
// select of own-vs-partner fragments).
__global__ __launch_bounds__(512, 4)
void jt_mlp_kernel(const int*   __restrict__ x,
                   const float* __restrict__ W1g, const float* __restrict__ b1g,
                   const float* __restrict__ W2g, const float* __restrict__ b2g,
                   const float* __restrict__ W3g, const float* __restrict__ b3g,
                   float* __restrict__ out)
{
    // Swizzled weights: element (row p, k) at p*rowlen + ch*8 + (k&7),
    //   W1: ch = (k>>3) ^ (p&7)
    //   W2: ch = (k>>3) ^ (p&15) ^ ((p&16)>>2)   (5th bit: kills the
    //       l31 vs l31+16 same-bank alias -> 8-access/bank minimum)
    __shared__ __align__(16) bf16 SW2[128 * 128];   // 32 KB
    __shared__ __align__(16) bf16 SWX[128 * 64];    // 16 KB: W1 staging, then HX
    __shared__ __align__(16) bf16 SW3[8 * 128];     // 2 KB
    __shared__ __align__(16) float LX[2][3][64][4]; // 6 KB (q>0 write, q==0 read)
    __shared__ __align__(16) bf16 OHLUT[16 * 8];    // 256 B one-hot fragments

    const int tid  = threadIdx.x;
    const int lane = tid & 63;
    const int ws   = __builtin_amdgcn_readfirstlane(tid >> 6);  // 0..7 scalar
    const int g    = ws >> 2;       // item group 0,1
    const int qs   = ws & 3;        // H quarter 0..3 (rows 32qs..32qs+31)
    const int l31  = lane & 31;
    const int lhi  = lane >> 5;
    const int kk   = l31 & 3;
    const int n    = blockIdx.x;    // clique (512 blocks, 2 resident/CU)

    const float* W1p = W1g + (size_t)n * (D_ * H_);
    const float* W2p = W2g + (size_t)n * (H_ * H_);
    const float* W3p = W3g + (size_t)n * (H_ * S_);
    const float* b1p = b1g + n * H_;
    const float* b2p = b2g + n * H_;
    const float* b3p = b3g + n * S_;

    const int p31 = swap23(l31);
    const bf16 one = (bf16)1.0f, zero = (bf16)0.0f;

    // ============ stage weights into LDS (coalesced float4; r8-proven) ============
    // One-hot LUT: entry 0 = zeros (sel=-1); entry j+1 = one-hot(j).
    if (tid < 16) {
        bf16x8 v;
#pragma unroll
        for (int j = 0; j < 8; ++j) v[j] = (tid == j + 1) ? one : zero;
        *(bf16x8*)&OHLUT[tid * 8] = v;
    }
    // W1 -> SWX (temporarily), staged by tid<256. k<8 rows carry +b1;
    // root n==0 zeroes k<32 first.
    if (tid < 256) {
        const int c0 = (tid & 31) * 4;
        const int k0 = (tid >> 5) * 8;          // 0..56
        float rows[8][4];
#pragma unroll
        for (int i = 0; i < 8; ++i) {
            float4 t4 = *(const float4*)(W1p + (k0 + i) * H_ + c0);
            if (n == 0 && k0 < 32) t4 = make_float4(0.f, 0.f, 0.f, 0.f);
            rows[i][0] = t4.x; rows[i][1] = t4.y; rows[i][2] = t4.z; rows[i][3] = t4.w;
        }
        if (k0 == 0) {
            const float4 bb = *(const float4*)(b1p + c0);
#pragma unroll
            for (int i = 0; i < 8; ++i) {
                rows[i][0] += bb.x; rows[i][1] += bb.y;
                rows[i][2] += bb.z; rows[i][3] += bb.w;
            }
        }
#pragma unroll
        for (int j2 = 0; j2 < 4; ++j2) {
            const int c = c0 + j2;
            const int p = (c & ~31) | swap23(c & 31);
            const int ch = (k0 >> 3) ^ (p & 7);
            bf16x4 lo, hi;
#pragma unroll
            for (int i = 0; i < 4; ++i) {
                lo[i] = (bf16)rows[i][j2];
                hi[i] = (bf16)rows[4 + i][j2];
            }
            *(bf16x4*)&SWX[p * 64 + ch * 8 + 0] = lo;
            *(bf16x4*)&SWX[p * 64 + ch * 8 + 4] = hi;
        }
    }
    // W2 -> SW2 (5-bit swizzle): all 512 threads, one 8-row block each
    {
        const int c0 = (tid & 31) * 4;
        const int k0 = (tid >> 5) * 8;          // 0..120
        float rows[8][4];
#pragma unroll
        for (int i = 0; i < 8; ++i) {
            const float4 t4 = *(const float4*)(W2p + (k0 + i) * H_ + c0);
            rows[i][0] = t4.x; rows[i][1] = t4.y; rows[i][2] = t4.z; rows[i][3] = t4.w;
        }
#pragma unroll
        for (int j2 = 0; j2 < 4; ++j2) {
            const int c = c0 + j2;
            const int p = (c & ~31) | swap23(c & 31);
            const int ch = (k0 >> 3) ^ (p & 15) ^ ((p & 16) >> 2);
            bf16x4 lo, hi;
#pragma unroll
            for (int i = 0; i < 4; ++i) {
                lo[i] = (bf16)rows[i][j2];
                hi[i] = (bf16)rows[4 + i][j2];
            }
            *(bf16x4*)&SW2[p * 128 + ch * 8 + 0] = lo;
            *(bf16x4*)&SW2[p * 128 + ch * 8 + 4] = hi;
        }
    }
    // W3^T[s][k] -> SW3
    if (tid < 128) {
        const int s = tid >> 4, kc = tid & 15, k0 = kc * 8;
        float vv[8];
#pragma unroll
        for (int i = 0; i < 8; ++i) vv[i] = W3p[(k0 + i) * S_ + s];
        const int ch = kc ^ s;
        bf16x4 lo, hi;
#pragma unroll
        for (int i = 0; i < 4; ++i) { lo[i] = (bf16)vv[i]; hi[i] = (bf16)vv[4 + i]; }
        *(bf16x4*)&SW3[s * 128 + ch * 8 + 0] = lo;
        *(bf16x4*)&SW3[s * 128 + ch * 8 + 4] = hi;
    }
    __syncthreads();

    // ---- W1 fragments for this wave's H-quarter (rows 32qs..32qs+31) ----
    bf16x8 w1f[4];
#pragma unroll
    for (int kt = 0; kt < 4; ++kt)
        w1f[kt] = *(const bf16x8*)
            &SWX[(32 * qs + l31) * 64 + (((kt << 1) + lhi) ^ (l31 & 7)) * 8];
    // ---- W3 fragments (this wave's chunks 2qs, 2qs+1) ----
    const int s2 = l31 & 7;   // lanes 8..31 duplicate state rows (outputs unused)
    bf16x8 w3f[2];
#pragma unroll
    for (int e = 0; e < 2; ++e)
        w3f[e] = *(const bf16x8*)
            &SW3[s2 * 128 + ((((2 * qs + e) << 1) + lhi) ^ s2) * 8];
    // ---- bias frags ----
    bf16x8 w2b, onef;
#pragma unroll
    for (int j = 0; j < 8; ++j) { w2b[j] = zero; onef[j] = zero; }
    w2b[0] = lhi ? zero : (bf16)b2p[32 * qs + p31];
    onef[0] = lhi ? zero : one;
    const float4 b3q = *(const float4*)(b3p + 4 * lhi);

    f32x16 zf;
#pragma unroll
    for (int i = 0; i < 16; ++i) zf[i] = 0.f;

    __syncthreads();   // w1f/w3f reads done -> SWX becomes the HX buffer
    bf16* HX = SWX;    // HX[g][gc][lane][8] = (g*8+gc)*512 + lane*8  (16 slots)

    // -------- x prefetch --------
    const int itbase = g * 8 + (l31 >> 2);
    int4 xo_c, xp_c;
    {
        const int* xb = x + (size_t)itbase * XROW + n * K_;
        xo_c = *(const int4*)xb;
        xp_c = (n > 0) ? *(const int4*)(xb - K_) : make_int4(0, 0, 0, 0);
    }

    const int swz = (l31 & 15) ^ ((l31 & 16) >> 2);
    const int pq  = (32 * qs + l31) * 128;    // W2 row base (C rows 32qs..+31)
    const int g8  = g * 8;

#pragma unroll 1
    for (int c = 0; c < NITER; ++c) {
        const int item = itbase + c * 16;
        const int4 xo = xo_c, xp = xp_c;
        if (c < NITER - 1) {
            const int* xb = x + (size_t)(item + 16) * XROW + n * K_;
            xo_c = *(const int4*)xb;
            xp_c = (n > 0) ? *(const int4*)(xb - K_) : make_int4(0, 0, 0, 0);
        }

        // ---- one-hot selectors (r3/r5-proven) ----
        int sel[4];
        sel[0] = (n > 0) ? (lhi ? xp.y : xp.x) : (lhi ? -1 : 0);
        sel[1] = (n > 0) ? (lhi ? xp.w : xp.z) : -1;
        sel[2] = (kk > (lhi ? 1 : 0)) ? (lhi ? xo.y : xo.x) : -1;
        sel[3] = (kk > (lhi ? 3 : 2)) ? (lhi ? xo.w : xo.z) : -1;

        // ---- layer 1: own H-quarter; one-hot B-frags from LUT ----
        f32x16 A = zf;
#pragma unroll
        for (int kt = 0; kt < 4; ++kt) {
            const bf16x8 bf1 = *(const bf16x8*)&OHLUT[(sel[kt] + 1) * 8];
            A = __builtin_amdgcn_mfma_f32_32x32x16_bf16(w1f[kt], bf1, A, 0, 0, 0);
        }

        // ---- extract own 2 chunks (2qs, 2qs+1), publish to group ----
#pragma unroll
        for (int e = 0; e < 2; ++e) {
            bf16x8 hf;
#pragma unroll
            for (int j = 0; j < 8; ++j)
                hf[j] = (bf16)fmaxf(A[8 * e + j], 0.f);
            *(bf16x8*)&HX[(g8 + 2 * qs + e) * 512 + lane * 8] = hf;
        }
        __syncthreads();

        // ---- layer 2: own C rows 32qs..+31; all 8 chunks read from HX ----
        f32x16 C = __builtin_amdgcn_mfma_f32_32x32x16_bf16(w2b, onef, zf, 0, 0, 0);
#pragma unroll
        for (int gc = 0; gc < 8; ++gc) {
            const bf16x8 hf = *(const bf16x8*)&HX[(g8 + gc) * 512 + lane * 8];
            const int chunk = ((gc << 1) + lhi) ^ swz;
            const bf16x8 f = *(const bf16x8*)&SW2[pq + chunk * 8];
            C = __builtin_amdgcn_mfma_f32_32x32x16_bf16(f, hf, C, 0, 0, 0);
        }

        // ---- layer 3 partial over own 2 chunks ----
        f32x16 L = zf;
#pragma unroll
        for (int e = 0; e < 2; ++e) {
            bf16x8 hg;
#pragma unroll
            for (int j = 0; j < 8; ++j)
                hg[j] = (bf16)fmaxf(C[8 * e + j], 0.f);
            L = __builtin_amdgcn_mfma_f32_32x32x16_bf16(w3f[e], hg, L, 0, 0, 0);
        }

        // ---- 4-way partial sum; epilogue on qs==0 ----
        if (qs != 0)
            *(float4*)&LX[g][qs - 1][lane][0] = make_float4(L[0], L[1], L[2], L[3]);
        __syncthreads();
        if (qs == 0) {
            const float4 P0 = *(const float4*)&LX[g][0][lane][0];
            const float4 P1 = *(const float4*)&LX[g][1][lane][0];
            const float4 P2 = *(const float4*)&LX[g][2][lane][0];
            float Ls0 = L[0] + P0.x + P1.x + P2.x + b3q.x;
            float Ls1 = L[1] + P0.y + P1.y + P2.y + b3q.y;
            float Ls2 = L[2] + P0.z + P1.z + P2.z + b3q.z;
            float Ls3 = L[3] + P0.w + P1.w + P2.w + b3q.w;

            float m4 = fmaxf(fmaxf(Ls0, Ls1), fmaxf(Ls2, Ls3));
            const float mm = fmaxf(m4, __shfl_xor(m4, 32));
            float e = __expf(Ls0 - mm) + __expf(Ls1 - mm) +
                      __expf(Ls2 - mm) + __expf(Ls3 - mm);
            const float ssum = e + __shfl_xor(e, 32);

            const int xs = (kk & 2) ? ((kk & 1) ? xo.w : xo.z)
                                    : ((kk & 1) ? xo.y : xo.x);
            const float own = (xs & 2) ? ((xs & 1) ? Ls3 : Ls2)
                                       : ((xs & 1) ? Ls1 : Ls0);
            const float oth = __shfl_xor(own, 32);
            const float obs = ((xs >> 2) == lhi) ? own : oth;
            float lp = obs - mm - __logf(ssum);
            lp += __shfl_xor(lp, 1);
            lp += __shfl_xor(lp, 2);
            if (lhi == 0 && kk == 0)
                out[(size_t)item * NC_ + n] = lp;
        }
        // HX overwrite next iter is safe: all HX reads complete before the
        // second barrier; LX reads (qs==0) complete before the next first
        // barrier (writers can't pass it until qs==0 arrives too).
    }
}

extern "C" void kernel_launch(void* const* d_in, const int* in_sizes, int n_in,
                              void* d_out, int out_size, void* d_ws, size_t ws_size,
                              hipStream_t stream) {
    const int*   x  = (const int*)d_in[0];
    const float* W1 = (const float*)d_in[1];
    const float* b1 = (const float*)d_in[2];
    const float* W2 = (const float*)d_in[3];
    const float* b2 = (const float*)d_in[4];
    const float* W3 = (const float*)d_in[5];
    const float* b3 = (const float*)d_in[6];
    float* out = (float*)d_out;
    jt_mlp_kernel<<<dim3(NC_), 512, 0, stream>>>(x, W1, b1, W2, b2, W3, b3, out);
}